// Round 1
// baseline (590.916 us; speedup 1.0000x reference)
//
#include <hip/hip_runtime.h>
#include <math.h>

#define NDIM 128

// One block per batch. 256 threads: thread (row = tid>>1, half = tid&1) owns
// Q[b][row][half*64 .. half*64+63] in 64 VGPRs (all indexing static/unrolled).
// Per-row scalars (x, r, u, CG state) are duplicated across the two half-threads;
// the 128-float matvec input vector is published to LDS and read back as
// broadcast float4 (2 unique addresses per wave -> conflict-free).
//
// Outer loop: damped Newton, exact replication of the reference's lk/gk logic.
// Inner solve: Jacobi-preconditioned CG on h = Q + diag(r/x^2) (never formed;
// matvec = Q*v + extra*v_row). Per-batch early exit at lk < 1e-5 (subsequent
// reference updates are bounded by ||dk|| <= lk since h >= I).

__global__ __launch_bounds__(256, 4)
void rpth_kernel(const float* __restrict__ Q,
                 const float* __restrict__ R,
                 float* __restrict__ out)
{
    const int b    = blockIdx.x;
    const int tid  = threadIdx.x;
    const int row  = tid >> 1;
    const int half = tid & 1;
    const int lane = tid & 63;
    const int wave = tid >> 6;

    __shared__ __align__(16) float s_vec[NDIM];
    __shared__ float s_red[8];

    const size_t qbase = (size_t)b * (NDIM * NDIM);
    const float* qrow  = Q + qbase + (size_t)row * NDIM + half * 64;

    float Qr[64];
#pragma unroll
    for (int c = 0; c < 16; ++c) {
        const float4 q4 = *reinterpret_cast<const float4*>(qrow + 4 * c);
        Qr[4*c+0] = q4.x; Qr[4*c+1] = q4.y; Qr[4*c+2] = q4.z; Qr[4*c+3] = q4.w;
    }
    const float qd = Q[qbase + (size_t)row * NDIM + row];
    const float rv = fabsf(R[b * NDIM + row]);

    float xv = rv / sqrtf(qd);          // x0 = ORTHANT * r / sqrt(diag(Q))

    const float FLc = 0.36286771f;      // 0.95*(3-sqrt(5))/2 in f32
    float lk = FLc + 1.0f;              // lk0

    // --- helpers ---------------------------------------------------------
    auto matvec = [&]() -> float {      // returns (Q * s_vec)[row], both halves
        float acc = 0.0f;
#pragma unroll
        for (int j = 0; j < 64; j += 4) {
            const float4 v4 = *reinterpret_cast<const float4*>(&s_vec[half * 64 + j]);
            acc = fmaf(Qr[j+0], v4.x, acc);
            acc = fmaf(Qr[j+1], v4.y, acc);
            acc = fmaf(Qr[j+2], v4.z, acc);
            acc = fmaf(Qr[j+3], v4.w, acc);
        }
        acc += __shfl_xor(acc, 1);      // combine the two half-row dots
        return acc;
    };

    auto block_sum = [&](float v) -> float {   // sum over all 256 threads
#pragma unroll
        for (int off = 32; off >= 1; off >>= 1)
            v += __shfl_xor(v, off);
        if (lane == 0) s_red[wave] = v;
        __syncthreads();
        const float s = (s_red[0] + s_red[1]) + (s_red[2] + s_red[3]);
        __syncthreads();
        return s;
    };

    auto block_max = [&](float v) -> float {   // max over all 256 threads (v >= 0)
#pragma unroll
        for (int off = 32; off >= 1; off >>= 1)
            v = fmaxf(v, __shfl_xor(v, off));
        if (lane == 0) s_red[wave] = v;
        __syncthreads();
        const float s = fmaxf(fmaxf(s_red[0], s_red[1]), fmaxf(s_red[2], s_red[3]));
        __syncthreads();
        return s;
    };
    // ---------------------------------------------------------------------

    for (int it = 0; it < 10; ++it) {
        if (half == 0) s_vec[row] = xv;
        __syncthreads();
        const float qx    = matvec();
        const float rx    = rv / xv;
        const float u     = qx - rx;             // u = Qx - r/x
        const float extra = rx / xv;             // r/x^2 (h = Q + diag(extra))
        const float hdiag = qd + extra;
        const float inv_hd = 1.0f / hdiag;       // Jacobi preconditioner

        // --- PCG: solve h * dk = u ---
        float dk  = 0.0f;
        float res = u;
        float z   = res * inv_hd;
        float p   = z;
        float rz  = block_sum(half == 0 ? res * z : 0.0f);
        const float rz0 = rz;

        if (rz0 > 1e-30f) {
            for (int cg = 0; cg < 24; ++cg) {
                if (half == 0) s_vec[row] = p;   // safe: >=1 barrier since last read
                __syncthreads();
                const float Ap  = matvec() + extra * p;
                const float pAp = block_sum(half == 0 ? p * Ap : 0.0f);
                const float alpha = rz / pAp;
                dk  = fmaf( alpha, p,  dk);
                res = fmaf(-alpha, Ap, res);
                z   = res * inv_hd;
                const float rz_new = block_sum(half == 0 ? res * z : 0.0f);
                if (rz_new <= 1e-10f * rz0 || rz_new <= 1e-32f) break;
                const float beta = rz_new / rz;
                p  = fmaf(beta, p, z);
                rz = rz_new;
            }
        }

        // --- damping / convergence bookkeeping (exact reference logic) ---
        const float gm  = block_max(half == 0 ? fabsf(dk / xv) : 0.0f);
        const float lkk = block_sum(half == 0 ? dk * u : 0.0f);
        const float gk     = (lk <= FLc) ? 0.0f : gm;
        const float lk_new = sqrtf(fmaxf(lkk, 0.0f));
        xv = xv - dk / (1.0f + gk);
        lk = lk_new;
        if (lk_new < 1e-5f) break;   // per-batch: subsequent ref updates <= 1e-5
    }

    // normalize: x / (sum|x| + 1e-8)
    const float sabs = block_sum(half == 0 ? fabsf(xv) : 0.0f);
    if (half == 0) out[b * NDIM + row] = xv / (sabs + 1e-8f);
}

extern "C" void kernel_launch(void* const* d_in, const int* in_sizes, int n_in,
                              void* d_out, int out_size, void* d_ws, size_t ws_size,
                              hipStream_t stream) {
    const float* Q = (const float*)d_in[0];
    const float* R = (const float*)d_in[1];
    float* out     = (float*)d_out;
    const int B    = in_sizes[1] / NDIM;   // r is [B, N, 1] -> B = 4096
    rpth_kernel<<<dim3(B), dim3(256), 0, stream>>>(Q, R, out);
}

// Round 2
// 589.953 us; speedup vs baseline: 1.0016x; 1.0016x over previous
//
#include <hip/hip_runtime.h>
#include <math.h>

#define NDIM 128

// One block per batch. 256 threads: thread (row = tid>>1, half = tid&1) owns
// Q[b][row][half*64 .. half*64+63] in 64 VGPRs. The empty asm "+v" pins break
// load-provenance so the compiler cannot rematerialize the Q loads (round-1
// failure mode: VGPR=52 -> Q re-read from L2 every matvec, ~15.7 GB L2 traffic).
//
// Outer loop: damped Newton (exact reference lk/gk logic), per-batch early
// exit at lk < 1e-5. Inner: Jacobi-PCG on h = Q + diag(r/x^2), 3 barriers/iter.

__global__ __launch_bounds__(256, 4)
void rpth_kernel(const float* __restrict__ Q,
                 const float* __restrict__ R,
                 float* __restrict__ out)
{
    const int b    = blockIdx.x;
    const int tid  = threadIdx.x;
    const int row  = tid >> 1;
    const int half = tid & 1;
    const int lane = tid & 63;
    const int wave = tid >> 6;

    __shared__ __align__(16) float s_vec[NDIM];
    __shared__ float s_red[8];

    const size_t qbase = (size_t)b * (NDIM * NDIM);
    const float* qrow  = Q + qbase + (size_t)row * NDIM + half * 64;

    float Qr[64];
#pragma unroll
    for (int c = 0; c < 16; ++c) {
        const float4 q4 = *reinterpret_cast<const float4*>(qrow + 4 * c);
        Qr[4*c+0] = q4.x; Qr[4*c+1] = q4.y; Qr[4*c+2] = q4.z; Qr[4*c+3] = q4.w;
    }
    // Pin: values become asm-defined -> compiler must keep them in VGPRs,
    // cannot re-issue the global loads inside the iteration loops.
#pragma unroll
    for (int j = 0; j < 64; ++j) asm volatile("" : "+v"(Qr[j]));

    const float qd = Q[qbase + (size_t)row * NDIM + row];
    const float rv = fabsf(R[b * NDIM + row]);

    float xv = rv / sqrtf(qd);          // x0 = ORTHANT * r / sqrt(diag(Q))

    const float FLc = 0.36286771f;      // 0.95*(3-sqrt(5))/2 in f32
    float lk = FLc + 1.0f;              // lk0

    auto matvec = [&]() -> float {      // (Q * s_vec)[row], combining halves
        float a0 = 0.f, a1 = 0.f, a2 = 0.f, a3 = 0.f;
#pragma unroll
        for (int j = 0; j < 64; j += 4) {
            const float4 v4 = *reinterpret_cast<const float4*>(&s_vec[half * 64 + j]);
            a0 = fmaf(Qr[j+0], v4.x, a0);
            a1 = fmaf(Qr[j+1], v4.y, a1);
            a2 = fmaf(Qr[j+2], v4.z, a2);
            a3 = fmaf(Qr[j+3], v4.w, a3);
        }
        float acc = (a0 + a1) + (a2 + a3);
        acc += __shfl_xor(acc, 1);      // combine the two half-row dots
        return acc;
    };

    auto wave_sum = [&](float v) -> float {
#pragma unroll
        for (int off = 32; off >= 1; off >>= 1) v += __shfl_xor(v, off);
        return v;
    };
    auto wave_max = [&](float v) -> float {
#pragma unroll
        for (int off = 32; off >= 1; off >>= 1) v = fmaxf(v, __shfl_xor(v, off));
        return v;
    };

    for (int it = 0; it < 10; ++it) {
        if (half == 0) s_vec[row] = xv;
        __syncthreads();                                   // (X)
        const float qx    = matvec();
        const float rx    = rv / xv;
        const float u     = qx - rx;                       // u = Qx - r/x
        const float extra = rx / xv;                       // r/x^2
        const float inv_hd = 1.0f / (qd + extra);          // Jacobi precond

        // --- PCG: solve (Q + diag(extra)) dk = u ---
        float dk  = 0.0f;
        float res = u;
        float z   = res * inv_hd;
        float p   = z;
        {   // rz0 reduction (slots 4..7; last read was before X)
            const float part = wave_sum(half == 0 ? res * z : 0.0f);
            if (lane == 0) s_red[4 + wave] = part;
        }
        __syncthreads();                                   // (Y)
        float rz = (s_red[4] + s_red[5]) + (s_red[6] + s_red[7]);
        const float rz0 = rz;

        if (rz0 > 1e-30f) {
            for (int cg = 0; cg < 24; ++cg) {
                if (half == 0) s_vec[row] = p;
                __syncthreads();                           // (A)
                const float Ap = matvec() + extra * p;
                {
                    const float part = wave_sum(half == 0 ? p * Ap : 0.0f);
                    if (lane == 0) s_red[wave] = part;
                }
                __syncthreads();                           // (B)
                const float pAp = (s_red[0] + s_red[1]) + (s_red[2] + s_red[3]);
                const float alpha = rz / pAp;
                dk  = fmaf( alpha, p,  dk);
                res = fmaf(-alpha, Ap, res);
                z   = res * inv_hd;
                {
                    const float part = wave_sum(half == 0 ? res * z : 0.0f);
                    if (lane == 0) s_red[4 + wave] = part;
                }
                __syncthreads();                           // (C)
                const float rz_new = (s_red[4] + s_red[5]) + (s_red[6] + s_red[7]);
                if (rz_new <= 1e-10f * rz0 || rz_new <= 1e-32f) break;
                const float beta = rz_new / rz;
                p  = fmaf(beta, p, z);
                rz = rz_new;
            }
        }

        // --- damping / convergence bookkeeping (fused gm & lkk) ---
        __syncthreads();                                   // (C2) protect s_red[4..7]
        {
            const float gpart = wave_max(half == 0 ? fabsf(dk / xv) : 0.0f);
            const float spart = wave_sum(half == 0 ? dk * u : 0.0f);
            if (lane == 0) { s_red[wave] = gpart; s_red[4 + wave] = spart; }
        }
        __syncthreads();                                   // (D)
        const float gm  = fmaxf(fmaxf(s_red[0], s_red[1]), fmaxf(s_red[2], s_red[3]));
        const float lkk = (s_red[4] + s_red[5]) + (s_red[6] + s_red[7]);
        const float gk     = (lk <= FLc) ? 0.0f : gm;
        const float lk_new = sqrtf(fmaxf(lkk, 0.0f));
        xv = xv - dk / (1.0f + gk);
        lk = lk_new;
        if (lk_new < 1e-5f) break;   // per-batch: remaining ref updates <= 1e-5
    }

    // normalize: x / (sum|x| + 1e-8)
    __syncthreads();
    {
        const float part = wave_sum(half == 0 ? fabsf(xv) : 0.0f);
        if (lane == 0) s_red[wave] = part;
    }
    __syncthreads();
    const float sabs = (s_red[0] + s_red[1]) + (s_red[2] + s_red[3]);
    if (half == 0) out[b * NDIM + row] = xv / (sabs + 1e-8f);
}

extern "C" void kernel_launch(void* const* d_in, const int* in_sizes, int n_in,
                              void* d_out, int out_size, void* d_ws, size_t ws_size,
                              hipStream_t stream) {
    const float* Q = (const float*)d_in[0];
    const float* R = (const float*)d_in[1];
    float* out     = (float*)d_out;
    const int B    = in_sizes[1] / NDIM;
    rpth_kernel<<<dim3(B), dim3(256), 0, stream>>>(Q, R, out);
}